// Round 2
// baseline (1176.019 us; speedup 1.0000x reference)
//
#include <hip/hip_runtime.h>
#include <cstdint>
#include <cstddef>

#define IN_C 128
#define HIDc 128
#define OUTc 64

using bf8 = __attribute__((ext_vector_type(8))) __bf16;
using f4  = __attribute__((ext_vector_type(4))) float;
using u32x4 = __attribute__((ext_vector_type(4))) unsigned int;

// ---- bf16 helpers (RNE) ----
__device__ __forceinline__ unsigned short f2bf(float f) {
    unsigned int u = __float_as_uint(f);
    unsigned int r = (u + 0x7FFFu + ((u >> 16) & 1u)) >> 16;
    return (unsigned short)r;
}
__device__ __forceinline__ float bf2f(unsigned short h) {
    return __uint_as_float(((unsigned int)h) << 16);
}

// Async global->LDS, 16 B per lane (guide §5, m97/m104): LDS dest is the
// wave-uniform base; HW places lane i's 16 B at base + i*16.
__device__ __forceinline__ void gload16(const unsigned short* g, unsigned short* l) {
    __builtin_amdgcn_global_load_lds(
        (const __attribute__((address_space(1))) unsigned int*)g,
        (__attribute__((address_space(3))) unsigned int*)l, 16, 0, 0);
}

// ---------------------------------------------------------------------------
// Graph build (battle-tested r3-r12).
// ---------------------------------------------------------------------------
__global__ void k_detect(const long long* ei, int n_nodes, int* flag) {
    int t = threadIdx.x;                    // blockDim = 64
    long long v = ei[t];
    int ok = (v >= 0 && v < (long long)n_nodes) ? 1 : 0;
    unsigned long long m = __ballot(ok);
    if (t == 0) *flag = (m == ~0ull) ? 1 : 0;
}

__global__ void k_cvt_hist(const void* ei, int twoE, int E, const int* flag,
                           int* __restrict__ out, int* __restrict__ deg, int n) {
    int i = blockIdx.x * blockDim.x + threadIdx.x;
    if (i >= twoE) return;
    int v = (*flag) ? (int)((const long long*)ei)[i] : ((const int*)ei)[i];
    out[i] = v;
    if (i >= E && (unsigned)v < (unsigned)n) atomicAdd(&deg[v], 1);
}

__global__ void k_dinv(const int* __restrict__ deg, float* __restrict__ dinv, int n) {
    int i = blockIdx.x * blockDim.x + threadIdx.x;
    if (i < n) dinv[i] = (deg[i] > 0) ? rsqrtf((float)deg[i]) : 0.0f;
}

__global__ void k_alloc(const int* __restrict__ deg, int* __restrict__ base,
                        int* __restrict__ cursor, int* __restrict__ counter, int n) {
    int i = blockIdx.x * blockDim.x + threadIdx.x;
    int lane = threadIdx.x & 63;
    int val = (i < n) ? deg[i] : 0;
    int scan = val;
    #pragma unroll
    for (int off = 1; off < 64; off <<= 1) {
        int t = __shfl_up(scan, off);
        if (lane >= off) scan += t;
    }
    int excl = scan - val;
    int total = __shfl(scan, 63);
    int wb = 0;
    if (lane == 0) wb = atomicAdd(counter, total);
    wb = __shfl(wb, 0);
    if (i < n) { base[i] = wb + excl; cursor[i] = wb + excl; }
}

__global__ void k_scatter(const int* __restrict__ eint, int E,
                          const float* __restrict__ dinv, int n,
                          int* __restrict__ cursor, int2* __restrict__ ew) {
    int e = blockIdx.x * blockDim.x + threadIdx.x;
    if (e >= E) return;
    int r = eint[e];
    int c = eint[E + e];
    if ((unsigned)r >= (unsigned)n || (unsigned)c >= (unsigned)n) return;
    int p = atomicAdd(&cursor[c], 1);
    int2 v; v.x = r; v.y = __float_as_int(dinv[r] * dinv[c]);
    ew[p] = v;
}

// ---------------------------------------------------------------------------
// Weight prep: W (nstack, K, N) fp32 -> Wt (nstack*N rows, K) bf16 (transposed).
// ---------------------------------------------------------------------------
__global__ void k_wprep(const float* __restrict__ W, unsigned short* __restrict__ Wt,
                        int K, int N) {
    int j = blockIdx.y;
    int idx = blockIdx.x * 256 + threadIdx.x;
    if (idx >= K * N) return;
    int k = idx / N, nn = idx - k * N;
    Wt[(size_t)j * N * K + (size_t)nn * K + k] = f2bf(W[(size_t)j * K * N + idx]);
}

__global__ void k_cast4(const float* __restrict__ x, unsigned short* __restrict__ y, int n4) {
    int i = blockIdx.x * 256 + threadIdx.x;
    if (i >= n4) return;
    float4 v = ((const float4*)x)[i];
    ushort4 o;
    o.x = f2bf(v.x); o.y = f2bf(v.y); o.z = f2bf(v.z); o.w = f2bf(v.w);
    ((ushort4*)y)[i] = o;
}

// ---------------------------------------------------------------------------
// m97-clone MFMA GEMM (r12 K-loop VERBATIM) + r13 LDS-staged epilogue.
// ---------------------------------------------------------------------------
template<int TILEN, bool BFOUT>
__global__ __launch_bounds__(256) void k_gemm(
    const unsigned short* __restrict__ A0, const unsigned short* __restrict__ A1,
    const unsigned short* __restrict__ A2, int W, int M, int K,
    const unsigned short* __restrict__ Bt,   // (npieces*TILEN) rows x K
    const float* __restrict__ bias,          // npieces*TILEN
    unsigned short* __restrict__ C0, int ldc0,
    unsigned short* __restrict__ C1, int ldc1,
    unsigned short* __restrict__ C2, int ldc2,
    float* __restrict__ Cf, int ldcf)
{
    constexpr int TM = 4;
    constexpr int TN = TILEN / 32;           // 4 or 2
    __shared__ __align__(16) unsigned short As[128 * 32];
    __shared__ __align__(16) unsigned short Bs[TILEN * 32];
    __shared__ __align__(16) unsigned char  Cs[16384];

    int t = threadIdx.x;
    int wave = t >> 6, lane = t & 63;
    int m16 = lane & 15, q = lane >> 4;
    int j = blockIdx.y;
    int row0 = blockIdx.x * 128;
    int wr = (wave & 1) * 64;
    int wc = (wave >> 1) * (TILEN / 2);

    int lr = lane >> 2, lch = lane & 3;
    int ra0 = (wave * 2 + 0) * 16 + lr;
    int ra1 = (wave * 2 + 1) * 16 + lr;
    int ga0 = row0 + ra0; if (ga0 >= M) ga0 = M - 1;
    int ga1 = row0 + ra1; if (ga1 >= M) ga1 = M - 1;
    size_t boff0 = (size_t)(j * TILEN + ra0) * K;
    size_t boff1 = (size_t)(j * TILEN + ra1) * K;
    size_t boffS = (size_t)(j * TILEN + wave * 16 + lr) * K;

    f4 acc[TM][TN];
    #pragma unroll
    for (int i = 0; i < TM; i++)
        #pragma unroll
        for (int jj = 0; jj < TN; jj++) acc[i][jj] = (f4){0.f, 0.f, 0.f, 0.f};

    for (int kk = 0; kk < K; kk += 32) {
        int pi = kk / W;
        const unsigned short* Ap = (pi == 0) ? A0 : ((pi == 1) ? A1 : A2);
        int kl = kk - pi * W;

        __syncthreads();
        gload16(&Ap[(size_t)ga0 * W + kl + lch * 8], &As[(wave * 2 + 0) * 512]);
        gload16(&Ap[(size_t)ga1 * W + kl + lch * 8], &As[(wave * 2 + 1) * 512]);
        if (TILEN == 128) {
            gload16(&Bt[boff0 + kk + lch * 8], &Bs[(wave * 2 + 0) * 512]);
            gload16(&Bt[boff1 + kk + lch * 8], &Bs[(wave * 2 + 1) * 512]);
        } else {
            gload16(&Bt[boffS + kk + lch * 8], &Bs[wave * 512]);
        }
        __syncthreads();

        bf8 af[TM], bfr[TN];
        #pragma unroll
        for (int tm = 0; tm < TM; tm++)
            af[tm] = *(const bf8*)&As[(wr + tm * 16 + m16) * 32 + q * 8];
        #pragma unroll
        for (int tn = 0; tn < TN; tn++)
            bfr[tn] = *(const bf8*)&Bs[(wc + tn * 16 + m16) * 32 + q * 8];
        #pragma unroll
        for (int tm = 0; tm < TM; tm++)
            #pragma unroll
            for (int tn = 0; tn < TN; tn++)
                acc[tm][tn] = __builtin_amdgcn_mfma_f32_16x16x32_bf16(
                    af[tm], bfr[tn], acc[tm][tn], 0, 0, 0);
    }

    // ---- epilogue: LDS-staged, full-line coalesced stores ----
    constexpr int EB  = BFOUT ? 2 : 4;
    constexpr int RB  = TILEN * EB;          // bytes per C row (<=256)
    constexpr int CPR = RB / 16;             // uint4 chunks per row
    constexpr int PT  = 64 * CPR / 256;      // chunks per thread per half
    char* Cb;
    long  ldb;
    if (BFOUT) {
        unsigned short* Cj = (j == 0) ? C0 : ((j == 1) ? C1 : C2);
        int lj = (j == 0) ? ldc0 : ((j == 1) ? ldc1 : ldc2);
        Cb = (char*)Cj; ldb = (long)lj * 2;
    } else {
        Cb = (char*)Cf; ldb = (long)ldcf * 4;
    }
    #pragma unroll
    for (int half = 0; half < 2; half++) {
        __syncthreads();
        if ((wave & 1) == half) {
            #pragma unroll
            for (int tn = 0; tn < TN; tn++) {
                int col = wc + tn * 16 + m16;
                float bi = bias[j * TILEN + col];
                #pragma unroll
                for (int tm = 0; tm < TM; tm++) {
                    #pragma unroll
                    for (int r = 0; r < 4; r++) {
                        int lrow = tm * 16 + q * 4 + r;
                        float v = acc[tm][tn][r] + bi;
                        if (BFOUT) ((unsigned short*)Cs)[lrow * TILEN + col] = f2bf(v);
                        else       ((float*)Cs)[lrow * TILEN + col] = v;
                    }
                }
            }
        }
        __syncthreads();
        #pragma unroll
        for (int i = 0; i < PT; i++) {
            int idx  = i * 256 + t;
            int lrow = idx / CPR;
            int c16  = idx - lrow * CPR;
            int grow = row0 + half * 64 + lrow;
            if (grow < M)
                *(uint4*)(Cb + (size_t)grow * ldb + c16 * 16) = ((const uint4*)Cs)[idx];
        }
    }
}

// ---------------------------------------------------------------------------
// r15: edge-packed dual SpMM + NON-TEMPORAL streams.
// r14 post-mortem: 2x MLP depth gave +2% only; FETCH pinned at 382 MB/3.35 TB/s
// across both structures -> gather-path service-rate wall. Remaining L2 lever:
// stop polluting L2 with the two STREAMS (ew reads 12.8 MB, output writes
// 50 MB) so gather rows (16x reuse, 51 MB WS) keep more of the 4 MB/XCD L2.
// ew loads + output stores marked non-temporal; gathers stay cached.
// ---------------------------------------------------------------------------
template<int PW>
__global__ __launch_bounds__(256) void k_spmm2v(
    const unsigned short* __restrict__ S,
    unsigned short* __restrict__ D1, unsigned short* __restrict__ D2,
    const int* __restrict__ base, const int* __restrict__ deg,
    const int2* __restrict__ ew, int n)
{
    constexpr int ROWB = 2 * PW;             // ushorts per source row (256/128)
    constexpr int GS   = ROWB / 8;           // lanes per edge: 8 ushorts=16B each
    constexpr int EP   = 64 / GS;            // edges per gather instr (2/4)
    constexpr int UN   = 16 / EP;            // gather instrs per iter (16 edges)

    int node = blockIdx.x * 4 + threadIdx.y;
    if (node >= n) return;
    int lane = threadIdx.x;                  // 0..63
    int sub  = lane / GS;                    // which packed edge
    int li   = lane % GS;                    // 16B chunk within the row
    const unsigned short* Sp = S + li * 8;

    float acc[8];
    #pragma unroll
    for (int v = 0; v < 8; v++) acc[v] = 0.f;

    int b = base[node], d = deg[node];
    if (d > 0) {
        int end = b + d;
        for (int e = b; e < end; e += UN * EP) {
            int row[UN]; float wt[UN];
            #pragma unroll
            for (int u = 0; u < UN; u++) {
                int myE = e + u * EP + sub;
                int cl  = myE < end ? myE : end - 1;
                unsigned long long ep = __builtin_nontemporal_load(
                    (const unsigned long long*)&ew[cl]);
                row[u] = (int)(ep & 0xffffffffull);
                wt[u]  = (myE < end) ? __uint_as_float((unsigned int)(ep >> 32)) : 0.f;
            }
            uint4 g[UN];
            #pragma unroll
            for (int u = 0; u < UN; u++)
                g[u] = *(const uint4*)(Sp + (size_t)row[u] * ROWB);
            #pragma unroll
            for (int u = 0; u < UN; u++) {
                float we = wt[u];
                const unsigned int* gw = (const unsigned int*)&g[u];
                #pragma unroll
                for (int p = 0; p < 4; p++) {
                    acc[2 * p]     += we * bf2f((unsigned short)(gw[p] & 0xffff));
                    acc[2 * p + 1] += we * bf2f((unsigned short)(gw[p] >> 16));
                }
            }
        }
    }
    // cross-pack reduction: packs are lanes differing in bits >= log2(GS)
    #pragma unroll
    for (int m = GS; m < 64; m <<= 1)
        #pragma unroll
        for (int v = 0; v < 8; v++) acc[v] += __shfl_xor(acc[v], m);

    if (lane < GS) {
        int cu = li * 8;                     // ushort col within the 2*PW row
        unsigned short* D = (cu < PW) ? (D1 + (size_t)node * PW + cu)
                                      : (D2 + (size_t)node * PW + (cu - PW));
        u32x4 o;
        o[0] = (unsigned)f2bf(acc[0]) | ((unsigned)f2bf(acc[1]) << 16);
        o[1] = (unsigned)f2bf(acc[2]) | ((unsigned)f2bf(acc[3]) << 16);
        o[2] = (unsigned)f2bf(acc[4]) | ((unsigned)f2bf(acc[5]) << 16);
        o[3] = (unsigned)f2bf(acc[6]) | ((unsigned)f2bf(acc[7]) << 16);
        __builtin_nontemporal_store(o, (u32x4*)D);
    }
}

// ---------------------------------------------------------------------------
// r15: edge-packed single-source SpMM + non-temporal streams.
// ---------------------------------------------------------------------------
template<int W>
__global__ __launch_bounds__(256) void k_spmmv(
    const unsigned short* __restrict__ S, unsigned short* __restrict__ D,
    const int* __restrict__ base, const int* __restrict__ deg,
    const int2* __restrict__ ew, int n)
{
    constexpr int GS = W / 8;                // lanes per edge (16/8)
    constexpr int EP = 64 / GS;              // edges per gather instr (4/8)
    constexpr int UN = (EP == 4) ? 4 : 2;    // 16 edges per iter

    int node = blockIdx.x * 4 + threadIdx.y;
    if (node >= n) return;
    int lane = threadIdx.x;
    int sub  = lane / GS;
    int li   = lane % GS;
    const unsigned short* Sp = S + li * 8;

    float acc[8];
    #pragma unroll
    for (int v = 0; v < 8; v++) acc[v] = 0.f;

    int b = base[node], d = deg[node];
    if (d > 0) {
        int end = b + d;
        for (int e = b; e < end; e += UN * EP) {
            int row[UN]; float wt[UN];
            #pragma unroll
            for (int u = 0; u < UN; u++) {
                int myE = e + u * EP + sub;
                int cl  = myE < end ? myE : end - 1;
                unsigned long long ep = __builtin_nontemporal_load(
                    (const unsigned long long*)&ew[cl]);
                row[u] = (int)(ep & 0xffffffffull);
                wt[u]  = (myE < end) ? __uint_as_float((unsigned int)(ep >> 32)) : 0.f;
            }
            uint4 g[UN];
            #pragma unroll
            for (int u = 0; u < UN; u++)
                g[u] = *(const uint4*)(Sp + (size_t)row[u] * W);
            #pragma unroll
            for (int u = 0; u < UN; u++) {
                float we = wt[u];
                const unsigned int* gw = (const unsigned int*)&g[u];
                #pragma unroll
                for (int p = 0; p < 4; p++) {
                    acc[2 * p]     += we * bf2f((unsigned short)(gw[p] & 0xffff));
                    acc[2 * p + 1] += we * bf2f((unsigned short)(gw[p] >> 16));
                }
            }
        }
    }
    #pragma unroll
    for (int m = GS; m < 64; m <<= 1)
        #pragma unroll
        for (int v = 0; v < 8; v++) acc[v] += __shfl_xor(acc[v], m);

    if (lane < GS) {
        u32x4 o;
        o[0] = (unsigned)f2bf(acc[0]) | ((unsigned)f2bf(acc[1]) << 16);
        o[1] = (unsigned)f2bf(acc[2]) | ((unsigned)f2bf(acc[3]) << 16);
        o[2] = (unsigned)f2bf(acc[4]) | ((unsigned)f2bf(acc[5]) << 16);
        o[3] = (unsigned)f2bf(acc[6]) | ((unsigned)f2bf(acc[7]) << 16);
        __builtin_nontemporal_store(o, (u32x4*)(D + (size_t)node * W + li * 8));
    }
}

// ---------------------------------------------------------------------------
// r15 BatchNorm: VECTORIZED stats + apply (old versions were 2 B/lane scalar
// loads — Common-mistake #2; ~2-2.5x slower than uint4 path).
// blockDim = 384: thread t -> octet o=t%48 (8 channels), row-group g=t/48 (8).
// ---------------------------------------------------------------------------
__global__ void k_bnstats_v(const unsigned short* __restrict__ p0,
                            const unsigned short* __restrict__ p1,
                            const unsigned short* __restrict__ p2,
                            float* __restrict__ sums, float* __restrict__ sumsq, int n)
{
    __shared__ float ls[384], ls2[384];
    int t = threadIdx.x;                     // 384
    ls[t] = 0.f; ls2[t] = 0.f;
    __syncthreads();
    int o = t % 48, g = t / 48;
    int pi = o >> 4, io = o & 15;
    const unsigned short* src = (pi == 0) ? p0 : ((pi == 1) ? p1 : p2);
    float s[8], s2[8];
    #pragma unroll
    for (int j = 0; j < 8; j++) { s[j] = 0.f; s2[j] = 0.f; }
    for (int r = blockIdx.x * 8 + g; r < n; r += gridDim.x * 8) {
        uint4 v = *(const uint4*)(src + (size_t)r * 128 + io * 8);
        const unsigned int* w = (const unsigned int*)&v;
        #pragma unroll
        for (int p = 0; p < 4; p++) {
            float a = bf2f((unsigned short)(w[p] & 0xffff));
            float b = bf2f((unsigned short)(w[p] >> 16));
            s[2 * p] += a;     s2[2 * p] += a * a;
            s[2 * p + 1] += b; s2[2 * p + 1] += b * b;
        }
    }
    #pragma unroll
    for (int j = 0; j < 8; j++) {
        atomicAdd(&ls[o * 8 + j], s[j]);
        atomicAdd(&ls2[o * 8 + j], s2[j]);
    }
    __syncthreads();
    atomicAdd(&sums[t], ls[t]);
    atomicAdd(&sumsq[t], ls2[t]);
}

__global__ void k_bnfin(const float* __restrict__ sums, const float* __restrict__ sumsq,
                        const float* __restrict__ g, const float* __restrict__ bb,
                        float* __restrict__ scale, float* __restrict__ shift,
                        int cat, float invn)
{
    int c = threadIdx.x;
    if (c >= cat) return;
    float mu  = sums[c] * invn;
    float var = sumsq[c] * invn - mu * mu;
    float sc  = g[c] * rsqrtf(var + 1e-5f);
    scale[c] = sc;
    shift[c] = bb[c] - mu * sc;
}

__global__ void k_bnapply_v(unsigned short* __restrict__ p0,
                            unsigned short* __restrict__ p1,
                            unsigned short* __restrict__ p2,
                            const float* __restrict__ scale,
                            const float* __restrict__ shift, int n)
{
    int t = threadIdx.x;                     // 384
    int o = t % 48, g = t / 48;
    int pi = o >> 4, io = o & 15;
    unsigned short* src = (pi == 0) ? p0 : ((pi == 1) ? p1 : p2);
    float sc[8], sh[8];
    #pragma unroll
    for (int j = 0; j < 8; j++) { sc[j] = scale[o * 8 + j]; sh[j] = shift[o * 8 + j]; }
    for (int r = blockIdx.x * 8 + g; r < n; r += gridDim.x * 8) {
        uint4 v = *(const uint4*)(src + (size_t)r * 128 + io * 8);
        unsigned int* w = (unsigned int*)&v;
        uint4 ov; unsigned int* ow = (unsigned int*)&ov;
        #pragma unroll
        for (int p = 0; p < 4; p++) {
            float a = fmaxf(bf2f((unsigned short)(w[p] & 0xffff)) * sc[2 * p] + sh[2 * p], 0.f);
            float b = fmaxf(bf2f((unsigned short)(w[p] >> 16)) * sc[2 * p + 1] + sh[2 * p + 1], 0.f);
            ow[p] = (unsigned)f2bf(a) | ((unsigned)f2bf(b) << 16);
        }
        *(uint4*)(src + (size_t)r * 128 + io * 8) = ov;
    }
}

// Diagnostic: if workspace is too small, surface ws_size (MB) via d_out.
__global__ void k_diag(float* out, float val, int n) {
    int i = blockIdx.x * blockDim.x + threadIdx.x;
    if (i < n) out[i] = val;
}

// ---------------------------------------------------------------------------
extern "C" void kernel_launch(void* const* d_in, const int* in_sizes, int n_in,
                              void* d_out, int out_size, void* d_ws, size_t ws_size,
                              hipStream_t stream)
{
    const float* x    = (const float*)d_in[0];
    const void*  ei   = d_in[1];
    const float* W0   = (const float*)d_in[2];
    const float* b0   = (const float*)d_in[3];
    const float* W1   = (const float*)d_in[4];
    const float* b1   = (const float*)d_in[5];
    const float* W2   = (const float*)d_in[6];
    const float* b2   = (const float*)d_in[7];
    const float* bn0g = (const float*)d_in[8];
    const float* bn0b = (const float*)d_in[9];
    const float* bn1g = (const float*)d_in[10];
    const float* bn1b = (const float*)d_in[11];
    const float* fpW  = (const float*)d_in[12];
    const float* fpb  = (const float*)d_in[13];
    float* out = (float*)d_out;

    const int N    = in_sizes[0] / IN_C;
    const int twoE = in_sizes[1];
    const int E    = twoE / 2;

    // ---- workspace carve (~184 MB; budget 256 MiB) ----
    char* p = (char*)d_ws;
    auto alloc = [&](size_t bytes) -> char* {
        char* r = p; p += (bytes + 255) & ~(size_t)255; return r;
    };
    // 6 contiguous N x 128 bf16 units; u1|u2 and u2-internal interleaving used.
    unsigned short* u0 = (unsigned short*)alloc((size_t)6 * N * 128 * 2);
    unsigned short* u1 = u0 + (size_t)1 * N * 128;
    unsigned short* u2 = u0 + (size_t)2 * N * 128;
    unsigned short* u3 = u0 + (size_t)3 * N * 128;
    unsigned short* u4 = u0 + (size_t)4 * N * 128;
    unsigned short* u5 = u0 + (size_t)5 * N * 128;
    unsigned short* Wt0 = (unsigned short*)alloc((size_t)3 * 128 * 128 * 2);
    unsigned short* Wt1 = (unsigned short*)alloc((size_t)3 * 384 * 128 * 2);
    unsigned short* Wt2 = (unsigned short*)alloc((size_t)3 * 384 * 64 * 2);
    unsigned short* WtF = (unsigned short*)alloc((size_t)192 * 64 * 2);
    float* dinv  = (float*)alloc((size_t)N * 4);
    int2*  ew    = (int2*)alloc((size_t)E * 8);
    float* sums  = (float*)alloc(2 * 384 * 4);
    float* sumsq = sums + 384;
    float* scale = (float*)alloc(384 * 4);
    float* shift = (float*)alloc(384 * 4);
    int* deg     = (int*)alloc((size_t)N * 4);
    int* base    = (int*)alloc((size_t)N * 4);
    int* cursor  = (int*)alloc((size_t)N * 4);
    int* eint    = (int*)alloc((size_t)twoE * 4);
    int* counter = (int*)alloc(4);
    int* flag    = (int*)alloc(4);

    size_t required = (size_t)(p - (char*)d_ws);
    if (required > ws_size) {
        k_diag<<<(out_size + 255) / 256, 256, 0, stream>>>(
            out, (float)(ws_size >> 20), out_size);
        return;
    }

    const int T = 256;
    dim3 spmm_blk(64, 4);
    int  spmm_grid = (N + 3) / 4;
    int  gx = (N + 127) / 128;

    // ---- weight prep + input cast ----
    k_wprep<<<dim3((128 * 128 + 255) / 256, 3), T, 0, stream>>>(W0, Wt0, 128, 128);
    k_wprep<<<dim3((384 * 128 + 255) / 256, 3), T, 0, stream>>>(W1, Wt1, 384, 128);
    k_wprep<<<dim3((384 * 64  + 255) / 256, 3), T, 0, stream>>>(W2, Wt2, 384, 64);
    k_wprep<<<dim3((192 * 64  + 255) / 256, 1), T, 0, stream>>>(fpW, WtF, 192, 64);
    unsigned short* Xb = u3;
    k_cast4<<<((N * 128 / 4) + 255) / 256, T, 0, stream>>>(x, Xb, N * 128 / 4);

    // ---- graph build ----
    hipMemsetAsync(deg, 0, (size_t)N * 4, stream);
    hipMemsetAsync(counter, 0, 4, stream);
    k_detect<<<1, 64, 0, stream>>>((const long long*)ei, N, flag);
    k_cvt_hist<<<(twoE + T - 1) / T, T, 0, stream>>>(ei, twoE, E, flag, eint, deg, N);
    k_dinv<<<(N + T - 1) / T, T, 0, stream>>>(deg, dinv, N);
    k_alloc<<<(N + T - 1) / T, T, 0, stream>>>(deg, base, cursor, counter, N);
    k_scatter<<<(E + T - 1) / T, T, 0, stream>>>(eint, E, dinv, N, cursor, ew);

    // ---- layer 0: Xb(u3) -> G0:u0 (plain), [G1|G2] interleaved in (u1,u2) ----
    k_gemm<128, true><<<dim3(gx, 3), T, 0, stream>>>(Xb, Xb, Xb, 128, N, 128,
        Wt0, b0, u0, 128, u1, 256, u1 + 128, 256, nullptr, 0);
    // dual: gather [G1|G2] -> H1:u4, T:u5 ; single: T -> H2:u3
    k_spmm2v<128><<<spmm_grid, spmm_blk, 0, stream>>>(u1, u4, u5, base, deg, ew, N);
    k_spmmv<128><<<spmm_grid, spmm_blk, 0, stream>>>(u5, u3, base, deg, ew, N);
    hipMemsetAsync(sums, 0, 2 * 384 * 4, stream);
    k_bnstats_v<<<2048, 384, 0, stream>>>(u0, u4, u3, sums, sumsq, N);
    k_bnfin<<<1, 384, 0, stream>>>(sums, sumsq, bn0g, bn0b, scale, shift, 384, 1.0f / N);
    k_bnapply_v<<<2048, 384, 0, stream>>>(u0, u4, u3, scale, shift, N);
    // layer-0 output: (u0, u4, u3)

    // ---- layer 1: (u0,u4,u3) -> G0':u5, [G1'|G2'] in (u1,u2) ----
    k_gemm<128, true><<<dim3(gx, 3), T, 0, stream>>>(u0, u4, u3, 128, N, 384,
        Wt1, b1, u5, 128, u1, 256, u1 + 128, 256, nullptr, 0);
    // dual: -> H1':u0, T':u4 ; single: T' -> H2':u3
    k_spmm2v<128><<<spmm_grid, spmm_blk, 0, stream>>>(u1, u0, u4, base, deg, ew, N);
    k_spmmv<128><<<spmm_grid, spmm_blk, 0, stream>>>(u4, u3, base, deg, ew, N);
    hipMemsetAsync(sums, 0, 2 * 384 * 4, stream);
    k_bnstats_v<<<2048, 384, 0, stream>>>(u5, u0, u3, sums, sumsq, N);
    k_bnfin<<<1, 384, 0, stream>>>(sums, sumsq, bn1g, bn1b, scale, shift, 384, 1.0f / N);
    k_bnapply_v<<<2048, 384, 0, stream>>>(u5, u0, u3, scale, shift, N);
    // layer-1 output: (u5, u0, u3)

    // ---- layer 2: (u5,u0,u3) -> L0:u1 (N x 64), [L1|L2] interleaved in u2 ----
    k_gemm<64, true><<<dim3(gx, 3), T, 0, stream>>>(u5, u0, u3, 128, N, 384,
        Wt2, b2, u1, 64, u2, 128, u2 + 64, 128, nullptr, 0);
    // dual: -> H1f:u4[0:N*64], T2:u4[N*64:] ; single: T2 -> H2f:u5[0:N*64]
    k_spmm2v<64><<<spmm_grid, spmm_blk, 0, stream>>>(u2, u4, u4 + (size_t)N * 64,
                                                     base, deg, ew, N);
    k_spmmv<64><<<spmm_grid, spmm_blk, 0, stream>>>(u4 + (size_t)N * 64, u5,
                                                    base, deg, ew, N);

    // ---- final projection: out = concat(u1, u4, u5)(N x 192) @ fpW + fpb ----
    k_gemm<64, false><<<dim3(gx, 1), T, 0, stream>>>(u1, u4, u5, 64, N, 192,
        WtF, fpb, nullptr, 0, nullptr, 0, nullptr, 0, out, 64);
}

// Round 3
// 1136.085 us; speedup vs baseline: 1.0352x; 1.0352x over previous
//
#include <hip/hip_runtime.h>
#include <cstdint>
#include <cstddef>

#define IN_C 128
#define HIDc 128
#define OUTc 64

using bf8 = __attribute__((ext_vector_type(8))) __bf16;
using f4  = __attribute__((ext_vector_type(4))) float;

// ---- bf16 helpers (RNE) ----
__device__ __forceinline__ unsigned short f2bf(float f) {
    unsigned int u = __float_as_uint(f);
    unsigned int r = (u + 0x7FFFu + ((u >> 16) & 1u)) >> 16;
    return (unsigned short)r;
}
__device__ __forceinline__ float bf2f(unsigned short h) {
    return __uint_as_float(((unsigned int)h) << 16);
}

// Async global->LDS, 16 B per lane (guide §5, m97/m104): LDS dest is the
// wave-uniform base; HW places lane i's 16 B at base + i*16.
__device__ __forceinline__ void gload16(const unsigned short* g, unsigned short* l) {
    __builtin_amdgcn_global_load_lds(
        (const __attribute__((address_space(1))) unsigned int*)g,
        (__attribute__((address_space(3))) unsigned int*)l, 16, 0, 0);
}

// ---------------------------------------------------------------------------
// Graph build (battle-tested r3-r12).
// ---------------------------------------------------------------------------
__global__ void k_detect(const long long* ei, int n_nodes, int* flag) {
    int t = threadIdx.x;                    // blockDim = 64
    long long v = ei[t];
    int ok = (v >= 0 && v < (long long)n_nodes) ? 1 : 0;
    unsigned long long m = __ballot(ok);
    if (t == 0) *flag = (m == ~0ull) ? 1 : 0;
}

__global__ void k_cvt_hist(const void* ei, int twoE, int E, const int* flag,
                           int* __restrict__ out, int* __restrict__ deg, int n) {
    int i = blockIdx.x * blockDim.x + threadIdx.x;
    if (i >= twoE) return;
    int v = (*flag) ? (int)((const long long*)ei)[i] : ((const int*)ei)[i];
    out[i] = v;
    if (i >= E && (unsigned)v < (unsigned)n) atomicAdd(&deg[v], 1);
}

__global__ void k_dinv(const int* __restrict__ deg, float* __restrict__ dinv, int n) {
    int i = blockIdx.x * blockDim.x + threadIdx.x;
    if (i < n) dinv[i] = (deg[i] > 0) ? rsqrtf((float)deg[i]) : 0.0f;
}

__global__ void k_alloc(const int* __restrict__ deg, int* __restrict__ base,
                        int* __restrict__ cursor, int* __restrict__ counter, int n) {
    int i = blockIdx.x * blockDim.x + threadIdx.x;
    int lane = threadIdx.x & 63;
    int val = (i < n) ? deg[i] : 0;
    int scan = val;
    #pragma unroll
    for (int off = 1; off < 64; off <<= 1) {
        int t = __shfl_up(scan, off);
        if (lane >= off) scan += t;
    }
    int excl = scan - val;
    int total = __shfl(scan, 63);
    int wb = 0;
    if (lane == 0) wb = atomicAdd(counter, total);
    wb = __shfl(wb, 0);
    if (i < n) { base[i] = wb + excl; cursor[i] = wb + excl; }
}

__global__ void k_scatter(const int* __restrict__ eint, int E,
                          const float* __restrict__ dinv, int n,
                          int* __restrict__ cursor, int2* __restrict__ ew) {
    int e = blockIdx.x * blockDim.x + threadIdx.x;
    if (e >= E) return;
    int r = eint[e];
    int c = eint[E + e];
    if ((unsigned)r >= (unsigned)n || (unsigned)c >= (unsigned)n) return;
    int p = atomicAdd(&cursor[c], 1);
    int2 v; v.x = r; v.y = __float_as_int(dinv[r] * dinv[c]);
    ew[p] = v;
}

// ---------------------------------------------------------------------------
// Weight prep: W (nstack, K, N) fp32 -> Wt (nstack*N rows, K) bf16 (transposed).
// ---------------------------------------------------------------------------
__global__ void k_wprep(const float* __restrict__ W, unsigned short* __restrict__ Wt,
                        int K, int N) {
    int j = blockIdx.y;
    int idx = blockIdx.x * 256 + threadIdx.x;
    if (idx >= K * N) return;
    int k = idx / N, nn = idx - k * N;
    Wt[(size_t)j * N * K + (size_t)nn * K + k] = f2bf(W[(size_t)j * K * N + idx]);
}

__global__ void k_cast4(const float* __restrict__ x, unsigned short* __restrict__ y, int n4) {
    int i = blockIdx.x * 256 + threadIdx.x;
    if (i >= n4) return;
    float4 v = ((const float4*)x)[i];
    ushort4 o;
    o.x = f2bf(v.x); o.y = f2bf(v.y); o.z = f2bf(v.z); o.w = f2bf(v.w);
    ((ushort4*)y)[i] = o;
}

// ---------------------------------------------------------------------------
// m97-clone MFMA GEMM (r12 K-loop VERBATIM) + r13 LDS-staged epilogue.
// r16: XCD-aware triplet remap (T1). With grid (gx8, 3), x-fastest dispatch
// puts the 3 piece-blocks sharing A-rows gx apart -> different XCD L2s, so
// A is L2-missed 3x. Remap hardware linear L: c=L&7 (XCD), s=L>>3 (slot);
// j=s%3, x=c+8*(s/3) -> the triplet (x, j=0..2) occupies consecutive slots
// of the SAME XCD => A-tile hits that XCD's L2 for pieces 2,3. Bijective
// for gx8 a multiple of 8 (pad tiles return early). npieces==1 unchanged.
// ---------------------------------------------------------------------------
template<int TILEN, bool BFOUT>
__global__ __launch_bounds__(256) void k_gemm(
    const unsigned short* __restrict__ A0, const unsigned short* __restrict__ A1,
    const unsigned short* __restrict__ A2, int W, int M, int K,
    const unsigned short* __restrict__ Bt,   // (npieces*TILEN) rows x K
    const float* __restrict__ bias,          // npieces*TILEN
    unsigned short* __restrict__ C0, int ldc0,
    unsigned short* __restrict__ C1, int ldc1,
    unsigned short* __restrict__ C2, int ldc2,
    float* __restrict__ Cf, int ldcf)
{
    constexpr int TM = 4;
    constexpr int TN = TILEN / 32;           // 4 or 2
    __shared__ __align__(16) unsigned short As[128 * 32];
    __shared__ __align__(16) unsigned short Bs[TILEN * 32];
    __shared__ __align__(16) unsigned char  Cs[16384];

    int bx, j;
    if (gridDim.y == 3) {
        int L = blockIdx.x + gridDim.x * blockIdx.y;   // hardware linear id
        int c = L & 7, s = L >> 3;
        j  = s % 3;
        bx = c + 8 * (s / 3);
        if (bx * 128 >= M) return;           // pad tile
    } else {
        bx = blockIdx.x; j = blockIdx.y;
    }

    int t = threadIdx.x;
    int wave = t >> 6, lane = t & 63;
    int m16 = lane & 15, q = lane >> 4;
    int row0 = bx * 128;
    int wr = (wave & 1) * 64;
    int wc = (wave >> 1) * (TILEN / 2);

    int lr = lane >> 2, lch = lane & 3;
    int ra0 = (wave * 2 + 0) * 16 + lr;
    int ra1 = (wave * 2 + 1) * 16 + lr;
    int ga0 = row0 + ra0; if (ga0 >= M) ga0 = M - 1;
    int ga1 = row0 + ra1; if (ga1 >= M) ga1 = M - 1;
    size_t boff0 = (size_t)(j * TILEN + ra0) * K;
    size_t boff1 = (size_t)(j * TILEN + ra1) * K;
    size_t boffS = (size_t)(j * TILEN + wave * 16 + lr) * K;

    f4 acc[TM][TN];
    #pragma unroll
    for (int i = 0; i < TM; i++)
        #pragma unroll
        for (int jj = 0; jj < TN; jj++) acc[i][jj] = (f4){0.f, 0.f, 0.f, 0.f};

    for (int kk = 0; kk < K; kk += 32) {
        int pi = kk / W;
        const unsigned short* Ap = (pi == 0) ? A0 : ((pi == 1) ? A1 : A2);
        int kl = kk - pi * W;

        __syncthreads();
        gload16(&Ap[(size_t)ga0 * W + kl + lch * 8], &As[(wave * 2 + 0) * 512]);
        gload16(&Ap[(size_t)ga1 * W + kl + lch * 8], &As[(wave * 2 + 1) * 512]);
        if (TILEN == 128) {
            gload16(&Bt[boff0 + kk + lch * 8], &Bs[(wave * 2 + 0) * 512]);
            gload16(&Bt[boff1 + kk + lch * 8], &Bs[(wave * 2 + 1) * 512]);
        } else {
            gload16(&Bt[boffS + kk + lch * 8], &Bs[wave * 512]);
        }
        __syncthreads();

        bf8 af[TM], bfr[TN];
        #pragma unroll
        for (int tm = 0; tm < TM; tm++)
            af[tm] = *(const bf8*)&As[(wr + tm * 16 + m16) * 32 + q * 8];
        #pragma unroll
        for (int tn = 0; tn < TN; tn++)
            bfr[tn] = *(const bf8*)&Bs[(wc + tn * 16 + m16) * 32 + q * 8];
        #pragma unroll
        for (int tm = 0; tm < TM; tm++)
            #pragma unroll
            for (int tn = 0; tn < TN; tn++)
                acc[tm][tn] = __builtin_amdgcn_mfma_f32_16x16x32_bf16(
                    af[tm], bfr[tn], acc[tm][tn], 0, 0, 0);
    }

    // ---- epilogue: LDS-staged, full-line coalesced stores ----
    constexpr int EB  = BFOUT ? 2 : 4;
    constexpr int RB  = TILEN * EB;          // bytes per C row (<=256)
    constexpr int CPR = RB / 16;             // uint4 chunks per row
    constexpr int PT  = 64 * CPR / 256;      // chunks per thread per half
    char* Cb;
    long  ldb;
    if (BFOUT) {
        unsigned short* Cj = (j == 0) ? C0 : ((j == 1) ? C1 : C2);
        int lj = (j == 0) ? ldc0 : ((j == 1) ? ldc1 : ldc2);
        Cb = (char*)Cj; ldb = (long)lj * 2;
    } else {
        Cb = (char*)Cf; ldb = (long)ldcf * 4;
    }
    #pragma unroll
    for (int half = 0; half < 2; half++) {
        __syncthreads();
        if ((wave & 1) == half) {
            #pragma unroll
            for (int tn = 0; tn < TN; tn++) {
                int col = wc + tn * 16 + m16;
                float bi = bias[j * TILEN + col];
                #pragma unroll
                for (int tm = 0; tm < TM; tm++) {
                    #pragma unroll
                    for (int r = 0; r < 4; r++) {
                        int lrow = tm * 16 + q * 4 + r;
                        float v = acc[tm][tn][r] + bi;
                        if (BFOUT) ((unsigned short*)Cs)[lrow * TILEN + col] = f2bf(v);
                        else       ((float*)Cs)[lrow * TILEN + col] = v;
                    }
                }
            }
        }
        __syncthreads();
        #pragma unroll
        for (int i = 0; i < PT; i++) {
            int idx  = i * 256 + t;
            int lrow = idx / CPR;
            int c16  = idx - lrow * CPR;
            int grow = row0 + half * 64 + lrow;
            if (grow < M)
                *(uint4*)(Cb + (size_t)grow * ldb + c16 * 16) = ((const uint4*)Cs)[idx];
        }
    }
}

// ---------------------------------------------------------------------------
// r14 edge-packed dual SpMM (r16: NT hints REVERTED — r15 showed NT stores
// evict the consumers' inputs from L2, +38 µs total; FETCH unchanged).
// 16 B/lane x 64 lanes = EP edges per gather instr; 16 edges/iter; tail
// masked via clamp-to-last + weight 0; cross-pack __shfl_xor reduce.
// ---------------------------------------------------------------------------
template<int PW>
__global__ __launch_bounds__(256) void k_spmm2v(
    const unsigned short* __restrict__ S,
    unsigned short* __restrict__ D1, unsigned short* __restrict__ D2,
    const int* __restrict__ base, const int* __restrict__ deg,
    const int2* __restrict__ ew, int n)
{
    constexpr int ROWB = 2 * PW;             // ushorts per source row (256/128)
    constexpr int GS   = ROWB / 8;           // lanes per edge: 8 ushorts=16B each
    constexpr int EP   = 64 / GS;            // edges per gather instr (2/4)
    constexpr int UN   = 16 / EP;            // gather instrs per iter (16 edges)

    int node = blockIdx.x * 4 + threadIdx.y;
    if (node >= n) return;
    int lane = threadIdx.x;                  // 0..63
    int sub  = lane / GS;                    // which packed edge
    int li   = lane % GS;                    // 16B chunk within the row
    const unsigned short* Sp = S + li * 8;

    float acc[8];
    #pragma unroll
    for (int v = 0; v < 8; v++) acc[v] = 0.f;

    int b = base[node], d = deg[node];
    if (d > 0) {
        int end = b + d;
        for (int e = b; e < end; e += UN * EP) {
            int row[UN]; float wt[UN];
            #pragma unroll
            for (int u = 0; u < UN; u++) {
                int myE = e + u * EP + sub;
                int cl  = myE < end ? myE : end - 1;
                int2 ev = ew[cl];
                row[u] = ev.x;
                wt[u]  = (myE < end) ? __int_as_float(ev.y) : 0.f;
            }
            uint4 g[UN];
            #pragma unroll
            for (int u = 0; u < UN; u++)
                g[u] = *(const uint4*)(Sp + (size_t)row[u] * ROWB);
            #pragma unroll
            for (int u = 0; u < UN; u++) {
                float we = wt[u];
                const unsigned int* gw = (const unsigned int*)&g[u];
                #pragma unroll
                for (int p = 0; p < 4; p++) {
                    acc[2 * p]     += we * bf2f((unsigned short)(gw[p] & 0xffff));
                    acc[2 * p + 1] += we * bf2f((unsigned short)(gw[p] >> 16));
                }
            }
        }
    }
    // cross-pack reduction: packs are lanes differing in bits >= log2(GS)
    #pragma unroll
    for (int m = GS; m < 64; m <<= 1)
        #pragma unroll
        for (int v = 0; v < 8; v++) acc[v] += __shfl_xor(acc[v], m);

    if (lane < GS) {
        int cu = li * 8;                     // ushort col within the 2*PW row
        unsigned short* D = (cu < PW) ? (D1 + (size_t)node * PW + cu)
                                      : (D2 + (size_t)node * PW + (cu - PW));
        uint4 o;
        o.x = (unsigned)f2bf(acc[0]) | ((unsigned)f2bf(acc[1]) << 16);
        o.y = (unsigned)f2bf(acc[2]) | ((unsigned)f2bf(acc[3]) << 16);
        o.z = (unsigned)f2bf(acc[4]) | ((unsigned)f2bf(acc[5]) << 16);
        o.w = (unsigned)f2bf(acc[6]) | ((unsigned)f2bf(acc[7]) << 16);
        *(uint4*)D = o;
    }
}

// ---------------------------------------------------------------------------
// r14 edge-packed single-source SpMM (r16: NT reverted).
// ---------------------------------------------------------------------------
template<int W>
__global__ __launch_bounds__(256) void k_spmmv(
    const unsigned short* __restrict__ S, unsigned short* __restrict__ D,
    const int* __restrict__ base, const int* __restrict__ deg,
    const int2* __restrict__ ew, int n)
{
    constexpr int GS = W / 8;                // lanes per edge (16/8)
    constexpr int EP = 64 / GS;              // edges per gather instr (4/8)
    constexpr int UN = (EP == 4) ? 4 : 2;    // 16 edges per iter

    int node = blockIdx.x * 4 + threadIdx.y;
    if (node >= n) return;
    int lane = threadIdx.x;
    int sub  = lane / GS;
    int li   = lane % GS;
    const unsigned short* Sp = S + li * 8;

    float acc[8];
    #pragma unroll
    for (int v = 0; v < 8; v++) acc[v] = 0.f;

    int b = base[node], d = deg[node];
    if (d > 0) {
        int end = b + d;
        for (int e = b; e < end; e += UN * EP) {
            int row[UN]; float wt[UN];
            #pragma unroll
            for (int u = 0; u < UN; u++) {
                int myE = e + u * EP + sub;
                int cl  = myE < end ? myE : end - 1;
                int2 ev = ew[cl];
                row[u] = ev.x;
                wt[u]  = (myE < end) ? __int_as_float(ev.y) : 0.f;
            }
            uint4 g[UN];
            #pragma unroll
            for (int u = 0; u < UN; u++)
                g[u] = *(const uint4*)(Sp + (size_t)row[u] * W);
            #pragma unroll
            for (int u = 0; u < UN; u++) {
                float we = wt[u];
                const unsigned int* gw = (const unsigned int*)&g[u];
                #pragma unroll
                for (int p = 0; p < 4; p++) {
                    acc[2 * p]     += we * bf2f((unsigned short)(gw[p] & 0xffff));
                    acc[2 * p + 1] += we * bf2f((unsigned short)(gw[p] >> 16));
                }
            }
        }
    }
    #pragma unroll
    for (int m = GS; m < 64; m <<= 1)
        #pragma unroll
        for (int v = 0; v < 8; v++) acc[v] += __shfl_xor(acc[v], m);

    if (lane < GS) {
        uint4 o;
        o.x = (unsigned)f2bf(acc[0]) | ((unsigned)f2bf(acc[1]) << 16);
        o.y = (unsigned)f2bf(acc[2]) | ((unsigned)f2bf(acc[3]) << 16);
        o.z = (unsigned)f2bf(acc[4]) | ((unsigned)f2bf(acc[5]) << 16);
        o.w = (unsigned)f2bf(acc[6]) | ((unsigned)f2bf(acc[7]) << 16);
        *(uint4*)(D + (size_t)node * W + li * 8) = o;
    }
}

// ---------------------------------------------------------------------------
// r15 BatchNorm: VECTORIZED stats + apply (kept in r16; uint4 = 16 B/lane).
// blockDim = 384: thread t -> octet o=t%48 (8 channels), row-group g=t/48 (8).
// ---------------------------------------------------------------------------
__global__ void k_bnstats_v(const unsigned short* __restrict__ p0,
                            const unsigned short* __restrict__ p1,
                            const unsigned short* __restrict__ p2,
                            float* __restrict__ sums, float* __restrict__ sumsq, int n)
{
    __shared__ float ls[384], ls2[384];
    int t = threadIdx.x;                     // 384
    ls[t] = 0.f; ls2[t] = 0.f;
    __syncthreads();
    int o = t % 48, g = t / 48;
    int pi = o >> 4, io = o & 15;
    const unsigned short* src = (pi == 0) ? p0 : ((pi == 1) ? p1 : p2);
    float s[8], s2[8];
    #pragma unroll
    for (int j = 0; j < 8; j++) { s[j] = 0.f; s2[j] = 0.f; }
    for (int r = blockIdx.x * 8 + g; r < n; r += gridDim.x * 8) {
        uint4 v = *(const uint4*)(src + (size_t)r * 128 + io * 8);
        const unsigned int* w = (const unsigned int*)&v;
        #pragma unroll
        for (int p = 0; p < 4; p++) {
            float a = bf2f((unsigned short)(w[p] & 0xffff));
            float b = bf2f((unsigned short)(w[p] >> 16));
            s[2 * p] += a;     s2[2 * p] += a * a;
            s[2 * p + 1] += b; s2[2 * p + 1] += b * b;
        }
    }
    #pragma unroll
    for (int j = 0; j < 8; j++) {
        atomicAdd(&ls[o * 8 + j], s[j]);
        atomicAdd(&ls2[o * 8 + j], s2[j]);
    }
    __syncthreads();
    atomicAdd(&sums[t], ls[t]);
    atomicAdd(&sumsq[t], ls2[t]);
}

__global__ void k_bnfin(const float* __restrict__ sums, const float* __restrict__ sumsq,
                        const float* __restrict__ g, const float* __restrict__ bb,
                        float* __restrict__ scale, float* __restrict__ shift,
                        int cat, float invn)
{
    int c = threadIdx.x;
    if (c >= cat) return;
    float mu  = sums[c] * invn;
    float var = sumsq[c] * invn - mu * mu;
    float sc  = g[c] * rsqrtf(var + 1e-5f);
    scale[c] = sc;
    shift[c] = bb[c] - mu * sc;
}

__global__ void k_bnapply_v(unsigned short* __restrict__ p0,
                            unsigned short* __restrict__ p1,
                            unsigned short* __restrict__ p2,
                            const float* __restrict__ scale,
                            const float* __restrict__ shift, int n)
{
    int t = threadIdx.x;                     // 384
    int o = t % 48, g = t / 48;
    int pi = o >> 4, io = o & 15;
    unsigned short* src = (pi == 0) ? p0 : ((pi == 1) ? p1 : p2);
    float sc[8], sh[8];
    #pragma unroll
    for (int j = 0; j < 8; j++) { sc[j] = scale[o * 8 + j]; sh[j] = shift[o * 8 + j]; }
    for (int r = blockIdx.x * 8 + g; r < n; r += gridDim.x * 8) {
        uint4 v = *(const uint4*)(src + (size_t)r * 128 + io * 8);
        unsigned int* w = (unsigned int*)&v;
        uint4 ov; unsigned int* ow = (unsigned int*)&ov;
        #pragma unroll
        for (int p = 0; p < 4; p++) {
            float a = fmaxf(bf2f((unsigned short)(w[p] & 0xffff)) * sc[2 * p] + sh[2 * p], 0.f);
            float b = fmaxf(bf2f((unsigned short)(w[p] >> 16)) * sc[2 * p + 1] + sh[2 * p + 1], 0.f);
            ow[p] = (unsigned)f2bf(a) | ((unsigned)f2bf(b) << 16);
        }
        *(uint4*)(src + (size_t)r * 128 + io * 8) = ov;
    }
}

// Diagnostic: if workspace is too small, surface ws_size (MB) via d_out.
__global__ void k_diag(float* out, float val, int n) {
    int i = blockIdx.x * blockDim.x + threadIdx.x;
    if (i < n) out[i] = val;
}

// ---------------------------------------------------------------------------
extern "C" void kernel_launch(void* const* d_in, const int* in_sizes, int n_in,
                              void* d_out, int out_size, void* d_ws, size_t ws_size,
                              hipStream_t stream)
{
    const float* x    = (const float*)d_in[0];
    const void*  ei   = d_in[1];
    const float* W0   = (const float*)d_in[2];
    const float* b0   = (const float*)d_in[3];
    const float* W1   = (const float*)d_in[4];
    const float* b1   = (const float*)d_in[5];
    const float* W2   = (const float*)d_in[6];
    const float* b2   = (const float*)d_in[7];
    const float* bn0g = (const float*)d_in[8];
    const float* bn0b = (const float*)d_in[9];
    const float* bn1g = (const float*)d_in[10];
    const float* bn1b = (const float*)d_in[11];
    const float* fpW  = (const float*)d_in[12];
    const float* fpb  = (const float*)d_in[13];
    float* out = (float*)d_out;

    const int N    = in_sizes[0] / IN_C;
    const int twoE = in_sizes[1];
    const int E    = twoE / 2;

    // ---- workspace carve (~184 MB; budget 256 MiB) ----
    char* p = (char*)d_ws;
    auto alloc = [&](size_t bytes) -> char* {
        char* r = p; p += (bytes + 255) & ~(size_t)255; return r;
    };
    // 6 contiguous N x 128 bf16 units; u1|u2 and u2-internal interleaving used.
    unsigned short* u0 = (unsigned short*)alloc((size_t)6 * N * 128 * 2);
    unsigned short* u1 = u0 + (size_t)1 * N * 128;
    unsigned short* u2 = u0 + (size_t)2 * N * 128;
    unsigned short* u3 = u0 + (size_t)3 * N * 128;
    unsigned short* u4 = u0 + (size_t)4 * N * 128;
    unsigned short* u5 = u0 + (size_t)5 * N * 128;
    unsigned short* Wt0 = (unsigned short*)alloc((size_t)3 * 128 * 128 * 2);
    unsigned short* Wt1 = (unsigned short*)alloc((size_t)3 * 384 * 128 * 2);
    unsigned short* Wt2 = (unsigned short*)alloc((size_t)3 * 384 * 64 * 2);
    unsigned short* WtF = (unsigned short*)alloc((size_t)192 * 64 * 2);
    float* dinv  = (float*)alloc((size_t)N * 4);
    int2*  ew    = (int2*)alloc((size_t)E * 8);
    float* sums  = (float*)alloc(2 * 384 * 4);
    float* sumsq = sums + 384;
    float* scale = (float*)alloc(384 * 4);
    float* shift = (float*)alloc(384 * 4);
    int* deg     = (int*)alloc((size_t)N * 4);
    int* base    = (int*)alloc((size_t)N * 4);
    int* cursor  = (int*)alloc((size_t)N * 4);
    int* eint    = (int*)alloc((size_t)twoE * 4);
    int* counter = (int*)alloc(4);
    int* flag    = (int*)alloc(4);

    size_t required = (size_t)(p - (char*)d_ws);
    if (required > ws_size) {
        k_diag<<<(out_size + 255) / 256, 256, 0, stream>>>(
            out, (float)(ws_size >> 20), out_size);
        return;
    }

    const int T = 256;
    dim3 spmm_blk(64, 4);
    int  spmm_grid = (N + 3) / 4;
    int  gx  = (N + 127) / 128;
    int  gx8 = ((gx + 7) / 8) * 8;           // padded for XCD triplet remap

    // ---- weight prep + input cast ----
    k_wprep<<<dim3((128 * 128 + 255) / 256, 3), T, 0, stream>>>(W0, Wt0, 128, 128);
    k_wprep<<<dim3((384 * 128 + 255) / 256, 3), T, 0, stream>>>(W1, Wt1, 384, 128);
    k_wprep<<<dim3((384 * 64  + 255) / 256, 3), T, 0, stream>>>(W2, Wt2, 384, 64);
    k_wprep<<<dim3((192 * 64  + 255) / 256, 1), T, 0, stream>>>(fpW, WtF, 192, 64);
    unsigned short* Xb = u3;
    k_cast4<<<((N * 128 / 4) + 255) / 256, T, 0, stream>>>(x, Xb, N * 128 / 4);

    // ---- graph build ----
    hipMemsetAsync(deg, 0, (size_t)N * 4, stream);
    hipMemsetAsync(counter, 0, 4, stream);
    k_detect<<<1, 64, 0, stream>>>((const long long*)ei, N, flag);
    k_cvt_hist<<<(twoE + T - 1) / T, T, 0, stream>>>(ei, twoE, E, flag, eint, deg, N);
    k_dinv<<<(N + T - 1) / T, T, 0, stream>>>(deg, dinv, N);
    k_alloc<<<(N + T - 1) / T, T, 0, stream>>>(deg, base, cursor, counter, N);
    k_scatter<<<(E + T - 1) / T, T, 0, stream>>>(eint, E, dinv, N, cursor, ew);

    // ---- layer 0: Xb(u3) -> G0:u0 (plain), [G1|G2] interleaved in (u1,u2) ----
    k_gemm<128, true><<<dim3(gx8, 3), T, 0, stream>>>(Xb, Xb, Xb, 128, N, 128,
        Wt0, b0, u0, 128, u1, 256, u1 + 128, 256, nullptr, 0);
    // dual: gather [G1|G2] -> H1:u4, T:u5 ; single: T -> H2:u3
    k_spmm2v<128><<<spmm_grid, spmm_blk, 0, stream>>>(u1, u4, u5, base, deg, ew, N);
    k_spmmv<128><<<spmm_grid, spmm_blk, 0, stream>>>(u5, u3, base, deg, ew, N);
    hipMemsetAsync(sums, 0, 2 * 384 * 4, stream);
    k_bnstats_v<<<2048, 384, 0, stream>>>(u0, u4, u3, sums, sumsq, N);
    k_bnfin<<<1, 384, 0, stream>>>(sums, sumsq, bn0g, bn0b, scale, shift, 384, 1.0f / N);
    k_bnapply_v<<<2048, 384, 0, stream>>>(u0, u4, u3, scale, shift, N);
    // layer-0 output: (u0, u4, u3)

    // ---- layer 1: (u0,u4,u3) -> G0':u5, [G1'|G2'] in (u1,u2) ----
    k_gemm<128, true><<<dim3(gx8, 3), T, 0, stream>>>(u0, u4, u3, 128, N, 384,
        Wt1, b1, u5, 128, u1, 256, u1 + 128, 256, nullptr, 0);
    // dual: -> H1':u0, T':u4 ; single: T' -> H2':u3
    k_spmm2v<128><<<spmm_grid, spmm_blk, 0, stream>>>(u1, u0, u4, base, deg, ew, N);
    k_spmmv<128><<<spmm_grid, spmm_blk, 0, stream>>>(u4, u3, base, deg, ew, N);
    hipMemsetAsync(sums, 0, 2 * 384 * 4, stream);
    k_bnstats_v<<<2048, 384, 0, stream>>>(u5, u0, u3, sums, sumsq, N);
    k_bnfin<<<1, 384, 0, stream>>>(sums, sumsq, bn1g, bn1b, scale, shift, 384, 1.0f / N);
    k_bnapply_v<<<2048, 384, 0, stream>>>(u5, u0, u3, scale, shift, N);
    // layer-1 output: (u5, u0, u3)

    // ---- layer 2: (u5,u0,u3) -> L0:u1 (N x 64), [L1|L2] interleaved in u2 ----
    k_gemm<64, true><<<dim3(gx8, 3), T, 0, stream>>>(u5, u0, u3, 128, N, 384,
        Wt2, b2, u1, 64, u2, 128, u2 + 64, 128, nullptr, 0);
    // dual: -> H1f:u4[0:N*64], T2:u4[N*64:] ; single: T2 -> H2f:u5[0:N*64]
    k_spmm2v<64><<<spmm_grid, spmm_blk, 0, stream>>>(u2, u4, u4 + (size_t)N * 64,
                                                     base, deg, ew, N);
    k_spmmv<64><<<spmm_grid, spmm_blk, 0, stream>>>(u4 + (size_t)N * 64, u5,
                                                    base, deg, ew, N);

    // ---- final projection: out = concat(u1, u4, u5)(N x 192) @ fpW + fpb ----
    k_gemm<64, false><<<dim3(gx, 1), T, 0, stream>>>(u1, u4, u5, 64, N, 192,
        WtF, fpb, nullptr, 0, nullptr, 0, nullptr, 0, out, 64);
}